// Round 13
// baseline (1712.336 us; speedup 1.0000x reference)
//
#include <hip/hip_runtime.h>
#include <stdint.h>
#include <math.h>

#define NIN    784
#define H1     100
#define H2     10
#define BATCH  4096
#define RT     8         // rows per block (2 blocks/CU)
#define WROWS  112       // padded N for W planes
#define WK     800       // padded K (25 tiles of 32)
#define AS     808       // A-plane row stride in halfs (404 dw == 20 mod 32)

typedef _Float16 h16;
typedef h16  h8  __attribute__((ext_vector_type(8)));
typedef h16  h2t __attribute__((ext_vector_type(2)));
typedef float f4 __attribute__((ext_vector_type(4)));

// ---- dynamic LDS layout (dwords) ----
#define L_A     0                    // 2 bufs x (hi,lo) x 8 x 404 = 12928
#define L_O1S   12928                // 2 x 800 = 1600
#define L_W2T   14528                // 1000
#define L_RED   15528                // 2 x 7 x 128 = 1792
#define L_SUMS  17320                // 80
#define L_KEYS  17400                // 200
#define L_TOTAL 17600                // 70,400 B -> 2 blocks/CU

// ---- Threefry-2x32 (jax partitionable path, verified R4+); C rotates ----
__device__ __forceinline__ void threefry2x32(uint32_t k0, uint32_t k1,
                                             uint32_t x0, uint32_t x1,
                                             uint32_t& o0, uint32_t& o1) {
    uint32_t ks2 = k0 ^ k1 ^ 0x1BD11BDAu;
    x0 += k0; x1 += k1;
#define TFR(r) { x0 += x1; x1 = __builtin_rotateleft32(x1, r); x1 ^= x0; }
    TFR(13) TFR(15) TFR(26) TFR(6)  x0 += k1;  x1 += ks2 + 1u;
    TFR(17) TFR(29) TFR(16) TFR(24) x0 += ks2; x1 += k0 + 2u;
    TFR(13) TFR(15) TFR(26) TFR(6)  x0 += k0;  x1 += k1 + 3u;
    TFR(17) TFR(29) TFR(16) TFR(24) x0 += k1;  x1 += ks2 + 4u;
    TFR(13) TFR(15) TFR(26) TFR(6)  x0 += ks2; x1 += k0 + 5u;
#undef TFR
    o0 = x0; o1 = x1;
}

__device__ __forceinline__ float u01(uint32_t b) {
    return __uint_as_float((b >> 9) | 0x3f800000u) - 1.0f;
}

// W1 -> transposed hi/lo f16 planes (lo pre-scaled x4096 to dodge f16 denorms)
__global__ void prep_w1(const float* __restrict__ W1, h16* __restrict__ w1hi,
                        h16* __restrict__ w1lo) {
    int idx = blockIdx.x * 256 + threadIdx.x;
    if (idx < WROWS * WK) {
        int h = idx / WK, k = idx - h * WK;
        float w = (h < H1 && k < NIN) ? W1[k * H1 + h] : 0.0f;
        h16 wh = (h16)w;
        h16 wl = (h16)((w - (float)wh) * 4096.0f);
        w1hi[idx] = wh; w1lo[idx] = wl;
    }
}

// NOTE: no min-waves clause! R12's (1024,8) forced a 64-reg unified budget
// (32 arch VGPRs) -> scratch spills in the hot loop (WRITE_SIZE 26.8 MB).
// Natural allocation is ~52-56 regs <= 64, so 8 waves/SIMD co-schedule anyway.
__global__ __launch_bounds__(1024)
void spiking_net_kernel(const float* __restrict__ x,
                        const h16* __restrict__ w1hi,
                        const h16* __restrict__ w1lo,
                        const float* __restrict__ b1,
                        const float* __restrict__ W2,
                        const float* __restrict__ b2,
                        float* __restrict__ out) {
    extern __shared__ __align__(16) float smem[];
    float*    const o1s  = smem + L_O1S;    // [2][8*100]
    float*    const w2t  = smem + L_W2T;
    float*    const red  = smem + L_RED;    // [2][7*128]
    float*    const sums = smem + L_SUMS;   // [80]
    uint32_t* const keys = (uint32_t*)(smem + L_KEYS);

    const int tid  = threadIdx.x;
    const int wv   = tid >> 6;
    const int lane = tid & 63;
    const int row0 = blockIdx.x * RT;

    // MFMA roles: waves 0..13 -> (Ntile = wv>>1, K-half = wv&1); 14,15 hash+layer2
    const bool mfm = (wv < 14);
    const int  nt  = wv >> 1;
    const int  kh  = wv & 1;

    // ---- init ----
    if (tid < 100) {
        uint32_t y0, y1;
        threefry2x32(0u, 42u, 0u, (uint32_t)tid, y0, y1);
        keys[2 * tid] = y0; keys[2 * tid + 1] = y1;
    }
    for (int i = tid; i < H2 * H1; i += 1024) {
        int cc2 = i / H1, k = i - cc2 * H1;
        w2t[i] = W2[k * H2 + cc2];
    }
    for (int i = tid; i < L_W2T; i += 1024) smem[i] = 0.0f;   // A planes + o1s bufs

    // MFMA per-lane constants; rows 8..15 of the M=16 tile are dead dupes
    const int  aoff = (lane & 7) * AS + (lane >> 4) * 8;      // A: m=(lane&15)&7
    const int  n    = (nt << 4) + (lane & 15);
    const int  boff = n * WK + (lane >> 4) * 8;               // B: n=lane&15, k=8*quad+j
    const bool nv   = (n < H1);
    const bool live = (lane < 32);                            // C quads 0,1 = rows 0..7
    const float b1v = (mfm && kh == 0 && live) ? b1[nv ? n : 0] : 0.0f;
    float i1[4] = {0.f, 0.f, 0.f, 0.f};                       // state on kh==0, lane<32

    // hash: wave pair covers row hr: half 0 -> dwords [0,192), half 1 -> [192,392)
    const int      hr  = wv & 7;
    const int      hf  = wv >> 3;
    const int      hkb = hf ? 192 : 0;
    const uint32_t rb  = (uint32_t)((row0 + hr) * NIN);
    const float*   xr  = x + (row0 + hr) * NIN;

    // layer2 on waves 14,15: u = pair index [0,128), active u < 80
    const bool l2w = (wv >= 14);
    const int  u   = l2w ? ((wv - 14) * 64 + lane) : 0;
    const bool l2a = l2w && (u < RT * H2);
    const int  r2  = u / 10, c2 = u - 10 * r2;
    const float b2r = l2a ? b2[c2] : 0.0f;
    float i2 = 0.f, sum2 = 0.f;

    __syncthreads();

    auto do_kd = [&](h16* ah, int kd, uint32_t hk0, uint32_t hk1) {
        uint32_t c0 = rb + (uint32_t)(2 * kd);
        uint32_t a0, a1, q0, q1;
        threefry2x32(hk0, hk1, 0u, c0,      a0, a1);
        threefry2x32(hk0, hk1, 0u, c0 + 1u, q0, q1);
        float2 xv = *(const float2*)(xr + 2 * kd);
        float v0 = u01(a0 ^ a1) * xv.x;
        float v1 = u01(q0 ^ q1) * xv.y;
        h16 hh0 = (h16)v0, hh1 = (h16)v1;            // bit-identical to R9/R10 path
        h16 ll0 = (h16)((v0 - (float)hh0) * 4096.0f);
        h16 ll1 = (h16)((v1 - (float)hh1) * 4096.0f);
        h2t ph; ph.x = hh0; ph.y = hh1;
        h2t pl; pl.x = ll0; pl.y = ll1;
        *(h2t*)(ah + 2 * kd) = ph;
        *(h2t*)(ah + 6464 + 2 * kd) = pl;            // lo plane = +3232 dw
    };
    auto hashrow = [&](int buf, uint32_t hk0, uint32_t hk1) {
        h16* ah = (h16*)smem + buf * 12928 + hr * AS;
#pragma unroll
        for (int it = 0; it < 3; ++it) do_kd(ah, hkb + (it << 6) + lane, hk0, hk1);
        if (hf && lane < 8) do_kd(ah, hkb + 192 + lane, hk0, hk1);
    };
    auto layer2 = [&](const float* orow) {
        const float* wrow = &w2t[c2 * H1];
        float a = 0.0f;
#pragma unroll
        for (int k = 0; k < H1; k += 4) {
            float4 ov = *(const float4*)&orow[k];
            float4 wq = *(const float4*)&wrow[k];
            a = fmaf(ov.x, wq.x, a); a = fmaf(ov.y, wq.y, a);
            a = fmaf(ov.z, wq.z, a); a = fmaf(ov.w, wq.w, a);
        }
        float inner2 = (a + b2r) + i2 * 0.9f;
        float outer2 = fmaxf(inner2 - 1.0f, 0.0f);
        inner2 = (outer2 > 0.0f) ? (inner2 - 1.5f * inner2) : inner2;
        i2 = inner2;
    };

    // prologue: xi(0) -> buf 0
    hashrow(0, keys[0], keys[1]);
    __syncthreads();

    f4 cc;   // MFMA result of step t, consumed (update) in phase t+1

    // phase t: update(t-1) | MFMA(t) | hash(t+1) | layer2(t-1)  -- one barrier
    for (int t = 0; t < 100; ++t) {
        // 1) neuron update for step t-1 (kh==0 waves, lanes<32)
        if (t >= 1 && t < 99 && mfm && kh == 0 && live) {
            f4 other = *(const f4*)(red + ((t - 1) & 1) * 896 + nt * 128 + lane * 4);
            float* op = o1s + ((t - 1) & 1) * 800;
#pragma unroll
            for (int rg = 0; rg < 4; ++rg) {
                float a  = (cc[rg] + other[rg]) + b1v;
                float in = a + i1[rg] * 0.9f;
                float o  = fmaxf(in - 1.0f, 0.0f);
                in = (o > 0.0f) ? (in - 1.5f * in) : in;
                i1[rg] = in;
                if (nv) op[((lane >> 4) * 4 + rg) * H1 + n] = o;   // rows 0..7
            }
        }
        // 2) MFMA for step t
        if (t < 98 && mfm) {
            const h16* Ah = (const h16*)smem + (t & 1) * 12928;
            const h16* Al = Ah + 6464;
            f4 accM = {0.f, 0.f, 0.f, 0.f};
            f4 accS = {0.f, 0.f, 0.f, 0.f};
            if (kh == 0) {
#pragma unroll
                for (int kt = 0; kt < 13; ++kt) {
                    h8 avh = *(const h8*)(Ah + aoff + kt * 32);
                    h8 avl = *(const h8*)(Al + aoff + kt * 32);
                    h8 bvh = *(const h8*)(w1hi + boff + kt * 32);
                    h8 bvl = *(const h8*)(w1lo + boff + kt * 32);
                    accM = __builtin_amdgcn_mfma_f32_16x16x32_f16(avh, bvh, accM, 0, 0, 0);
                    accS = __builtin_amdgcn_mfma_f32_16x16x32_f16(avl, bvh, accS, 0, 0, 0);
                    accS = __builtin_amdgcn_mfma_f32_16x16x32_f16(avh, bvl, accS, 0, 0, 0);
                }
            } else {
#pragma unroll
                for (int kt = 13; kt < 25; ++kt) {
                    h8 avh = *(const h8*)(Ah + aoff + kt * 32);
                    h8 avl = *(const h8*)(Al + aoff + kt * 32);
                    h8 bvh = *(const h8*)(w1hi + boff + kt * 32);
                    h8 bvl = *(const h8*)(w1lo + boff + kt * 32);
                    accM = __builtin_amdgcn_mfma_f32_16x16x32_f16(avh, bvh, accM, 0, 0, 0);
                    accS = __builtin_amdgcn_mfma_f32_16x16x32_f16(avl, bvh, accS, 0, 0, 0);
                    accS = __builtin_amdgcn_mfma_f32_16x16x32_f16(avh, bvl, accS, 0, 0, 0);
                }
            }
            cc = accM + accS * 0.000244140625f;    // + accS/4096
            if (kh == 1 && live)
                *(f4*)(red + (t & 1) * 896 + nt * 128 + lane * 4) = cc;
        }
        // 3) hash xi for step t+1
        if (t < 97) hashrow((t + 1) & 1, keys[2 * (t + 1)], keys[2 * (t + 1) + 1]);
        // 4) layer2 for step t-1 (reads outer1(t-2) = o1s[t&1])
        if (t >= 1 && l2a) {
            layer2(o1s + (t & 1) * 800 + r2 * H1);
            if (t >= 20) sum2 += i2;               // step s=t-1 >= 19
        }
        __syncthreads();
    }

    // ---- epilogue: log_softmax ----
    if (l2a) sums[u] = sum2;
    __syncthreads();
    if (tid < RT * H2) {
        const int rr = tid / 10, ccl = tid - 10 * rr;
        float m = -INFINITY;
#pragma unroll
        for (int cc2 = 0; cc2 < H2; ++cc2) m = fmaxf(m, sums[rr * H2 + cc2]);
        float s = 0.0f;
#pragma unroll
        for (int cc2 = 0; cc2 < H2; ++cc2) s += expf(sums[rr * H2 + cc2] - m);
        out[(row0 + rr) * H2 + ccl] = sums[rr * H2 + ccl] - m - logf(s);
    }
}

extern "C" void kernel_launch(void* const* d_in, const int* in_sizes, int n_in,
                              void* d_out, int out_size, void* d_ws, size_t ws_size,
                              hipStream_t stream) {
    const float* x  = (const float*)d_in[0];
    const float* W1 = (const float*)d_in[1];
    const float* b1 = (const float*)d_in[2];
    const float* W2 = (const float*)d_in[3];
    const float* b2 = (const float*)d_in[4];
    float* out = (float*)d_out;
    h16* w1hi = (h16*)d_ws;                          // 179,200 B
    h16* w1lo = w1hi + WROWS * WK;                   // ws total 358,400 B

    hipLaunchKernelGGL(prep_w1, dim3((WROWS * WK + 255) / 256), dim3(256), 0, stream,
                       W1, w1hi, w1lo);

    const size_t lds_bytes = (size_t)L_TOTAL * 4;    // 70,400 B -> 2 blocks/CU
    hipFuncSetAttribute((const void*)spiking_net_kernel,
                        hipFuncAttributeMaxDynamicSharedMemorySize, (int)lds_bytes);
    // 512 blocks x 1024 threads; LDS allows 2 blocks/CU = 32 waves/CU if regs <= 64
    hipLaunchKernelGGL(spiking_net_kernel, dim3(BATCH / RT), dim3(1024), lds_bytes, stream,
                       x, w1hi, w1lo, b1, W2, b2, out);
}

// Round 14
// 1034.635 us; speedup vs baseline: 1.6550x; 1.6550x over previous
//
#include <hip/hip_runtime.h>
#include <stdint.h>
#include <math.h>

#define NIN    784
#define H1     100
#define H2     10
#define BATCH  4096
#define RT     16       // rows per block
#define WROWS  112      // padded N for W planes
#define WK     800      // padded K (25 tiles of 32)
#define AS     808      // A-plane row stride in halfs (404 dw == 20 mod 32)

typedef _Float16 h16;
typedef h16  h8  __attribute__((ext_vector_type(8)));
typedef h16  h2t __attribute__((ext_vector_type(2)));
typedef float f4 __attribute__((ext_vector_type(4)));

// ---- dynamic LDS layout (dwords) ----
#define L_A     0                    // 2 bufs x (hi,lo) x 16 x 404 = 25856
#define L_O1S   25856                // 2 x 1600 = 3200
#define L_W2T   29056                // 1000
#define L_RED   30056                // 2 x 7 x 256 = 3584
#define L_SUMS  33640                // 160
#define L_KEYS  33800                // 200
#define L_TOTAL 34000                // 136,000 B

// ---- Threefry-2x32 (jax partitionable path, verified R4+) ----
__device__ __forceinline__ void threefry2x32(uint32_t k0, uint32_t k1,
                                             uint32_t x0, uint32_t x1,
                                             uint32_t& o0, uint32_t& o1) {
    uint32_t ks2 = k0 ^ k1 ^ 0x1BD11BDAu;
    x0 += k0; x1 += k1;
#define TFR(r) { x0 += x1; x1 = __builtin_rotateleft32(x1, r); x1 ^= x0; }
    TFR(13) TFR(15) TFR(26) TFR(6)  x0 += k1;  x1 += ks2 + 1u;
    TFR(17) TFR(29) TFR(16) TFR(24) x0 += ks2; x1 += k0 + 2u;
    TFR(13) TFR(15) TFR(26) TFR(6)  x0 += k0;  x1 += k1 + 3u;
    TFR(17) TFR(29) TFR(16) TFR(24) x0 += k1;  x1 += ks2 + 4u;
    TFR(13) TFR(15) TFR(26) TFR(6)  x0 += ks2; x1 += k0 + 5u;
#undef TFR
    o0 = x0; o1 = x1;
}

__device__ __forceinline__ float u01(uint32_t b) {
    return __uint_as_float((b >> 9) | 0x3f800000u) - 1.0f;
}

// W1 -> transposed hi/lo f16 planes (lo pre-scaled x4096 to dodge f16 denorms)
__global__ void prep_w1(const float* __restrict__ W1, h16* __restrict__ w1hi,
                        h16* __restrict__ w1lo) {
    int idx = blockIdx.x * 256 + threadIdx.x;
    if (idx < WROWS * WK) {
        int h = idx / WK, k = idx - h * WK;
        float w = (h < H1 && k < NIN) ? W1[k * H1 + h] : 0.0f;
        h16 wh = (h16)w;
        h16 wl = (h16)((w - (float)wh) * 4096.0f);
        w1hi[idx] = wh; w1lo[idx] = wl;
    }
}

__global__ __launch_bounds__(1024)
void spiking_net_kernel(const float* __restrict__ x,
                        const h16* __restrict__ w1hi,
                        const h16* __restrict__ w1lo,
                        const float* __restrict__ b1,
                        const float* __restrict__ W2,
                        const float* __restrict__ b2,
                        float* __restrict__ out) {
    extern __shared__ __align__(16) float smem[];
    float*    const o1s  = smem + L_O1S;    // [2][16*100]
    float*    const w2t  = smem + L_W2T;
    float*    const red  = smem + L_RED;    // [2][7*256]
    float*    const sums = smem + L_SUMS;
    uint32_t* const keys = (uint32_t*)(smem + L_KEYS);

    const int tid  = threadIdx.x;
    const int wv   = tid >> 6;
    const int lane = tid & 63;
    const int row0 = blockIdx.x * RT;

    // roles: waves 0..13 MFMA (nt = wv>>1, kh = wv&1) + hash; 14,15 hash + layer2
    const bool mfm = (wv < 14);
    const int  nt  = wv >> 1;
    const int  kh  = wv & 1;

    // ---- init ----
    if (tid < 100) {
        uint32_t y0, y1;
        threefry2x32(0u, 42u, 0u, (uint32_t)tid, y0, y1);
        keys[2 * tid] = y0; keys[2 * tid + 1] = y1;
    }
    for (int i = tid; i < H2 * H1; i += 1024) {
        int cc2 = i / H1, k = i - cc2 * H1;
        w2t[i] = W2[k * H2 + cc2];
    }
    for (int i = tid; i < 2 * RT * H1; i += 1024) o1s[i] = 0.0f;
    for (int i = tid; i < L_O1S; i += 1024) smem[i] = 0.0f;        // A planes (K-pad)

    // MFMA per-lane constants
    const int  aoff = (lane & 15) * AS + (lane >> 4) * 8;     // A: m=lane&15, k=8*quad+j
    const int  n    = (nt << 4) + (lane & 15);
    const int  boff = n * WK + (lane >> 4) * 8;               // B: n=lane&15, k=8*quad+j
    const bool nv   = (n < H1);
    const float b1v = (mfm && kh == 0) ? b1[nv ? n : 0] : 0.0f;
    float i1[4] = {0.f, 0.f, 0.f, 0.f};                       // state on kh==0 waves

    // hash: wave w owns row w
    const int      hrow = wv;
    const uint32_t rb   = (uint32_t)((row0 + hrow) * NIN);
    const float*   xr   = x + (row0 + hrow) * NIN;

    // layer2 on waves 14,15: u in [0,128); lanes u in [48,80) also take 128+u-48
    const bool l2w = (wv >= 14);
    const int  u   = l2w ? ((wv - 14) * 64 + lane) : 0;
    const bool l2b = l2w && (u >= 48 && u < 80);
    const int  pa  = u;
    const int  pb  = l2b ? (128 + u - 48) : 0;
    const int  r2a = pa / 10, c2a = pa - 10 * r2a;
    const int  r2b = pb / 10, c2b = pb - 10 * r2b;
    const float b2a = l2w ? b2[c2a] : 0.0f;
    const float b2b = l2b ? b2[c2b] : 0.0f;
    float i2a = 0.f, s2a = 0.f, i2b = 0.f, s2b = 0.f;

    __syncthreads();

    // one hash unit: dword-pair kd = it*64+lane of this wave's row
    auto do_kd = [&](h16* ah, int it, uint32_t hk0, uint32_t hk1) {
        int kd = (it << 6) + lane;
        if (it < 6 || lane < 8) {
            uint32_t c0 = rb + (uint32_t)(2 * kd);
            uint32_t a0, a1, q0, q1;
            threefry2x32(hk0, hk1, 0u, c0,      a0, a1);
            threefry2x32(hk0, hk1, 0u, c0 + 1u, q0, q1);
            float2 xv = *(const float2*)(xr + 2 * kd);
            float v0 = u01(a0 ^ a1) * xv.x;
            float v1 = u01(q0 ^ q1) * xv.y;
            h16 hh0 = (h16)v0, hh1 = (h16)v1;            // bit-identical to R9+
            h16 ll0 = (h16)((v0 - (float)hh0) * 4096.0f);
            h16 ll1 = (h16)((v1 - (float)hh1) * 4096.0f);
            h2t ph; ph.x = hh0; ph.y = hh1;
            h2t pl; pl.x = ll0; pl.y = ll1;
            *(h2t*)(ah + 2 * kd) = ph;
            *(h2t*)(ah + 12928 + 2 * kd) = pl;           // lo plane = +6464 dw
        }
    };
    auto layer2 = [&](const float* orow, float wb2, float& i2, float& s2,
                      int c2, bool dosum) {
        const float* wrow = &w2t[c2 * H1];
        float a = 0.0f;
#pragma unroll
        for (int k = 0; k < H1; k += 4) {
            float4 ov = *(const float4*)&orow[k];
            float4 wq = *(const float4*)&wrow[k];
            a = fmaf(ov.x, wq.x, a); a = fmaf(ov.y, wq.y, a);
            a = fmaf(ov.z, wq.z, a); a = fmaf(ov.w, wq.w, a);
        }
        float inner2 = (a + wb2) + i2 * 0.9f;
        float outer2 = fmaxf(inner2 - 1.0f, 0.0f);
        inner2 = (outer2 > 0.0f) ? (inner2 - 1.5f * inner2) : inner2;
        i2 = inner2;
        if (dosum) s2 += inner2;
    };

    // prologue: xi(0) -> buf 0
    {
        h16* ah = (h16*)(smem + 0) + hrow * AS;
#pragma unroll
        for (int it = 0; it < 7; ++it) do_kd(ah, it, keys[0], keys[1]);
    }
    __syncthreads();

    f4 cc;   // MFMA result of step t, consumed (update) in phase t+1

    // phase t: update(t-1) | fused MFMA(t)+hash(t+1) | layer2(t-1)  -- one barrier
    for (int t = 0; t < 100; ++t) {
        const bool domf = (t < 98);
        const bool doh  = (t < 97);
        const uint32_t hk0 = keys[2 * (t + 1)], hk1 = keys[2 * (t + 1) + 1];

        if (mfm) {
            // 1) neuron update for step t-1 (kh==0 waves)
            if (t >= 1 && t < 99 && kh == 0) {
                f4 other = *(const f4*)(red + ((t - 1) & 1) * 1792 + nt * 256 + lane * 4);
                float* op = o1s + ((t - 1) & 1) * 1600;
#pragma unroll
                for (int rg = 0; rg < 4; ++rg) {
                    float a  = (cc[rg] + other[rg]) + b1v;
                    float in = a + i1[rg] * 0.9f;
                    float o  = fmaxf(in - 1.0f, 0.0f);
                    in = (o > 0.0f) ? (in - 1.5f * in) : in;
                    i1[rg] = in;
                    if (nv) op[((lane >> 4) * 4 + rg) * H1 + n] = o;   // row=quad*4+reg
                }
            }
            // 2) fused: MFMA(t) on A[t&1] interleaved with hash(t+1) into A[(t+1)&1]
            const h16* Ah = (const h16*)(smem + (t & 1) * 12928);
            const h16* Al = Ah + 12928;
            h16* hw = (h16*)(smem + ((t + 1) & 1) * 12928) + hrow * AS;
            f4 accM = {0.f, 0.f, 0.f, 0.f};
            f4 accS = {0.f, 0.f, 0.f, 0.f};
            if (kh == 0) {
#pragma unroll
                for (int j = 0; j < 13; ++j) {
                    if (doh && j < 7) do_kd(hw, j, hk0, hk1);
                    if (domf) {
                        const int kt = j;
                        h8 avh = *(const h8*)(Ah + aoff + kt * 32);
                        h8 avl = *(const h8*)(Al + aoff + kt * 32);
                        h8 bvh = *(const h8*)(w1hi + boff + kt * 32);
                        h8 bvl = *(const h8*)(w1lo + boff + kt * 32);
                        accM = __builtin_amdgcn_mfma_f32_16x16x32_f16(avh, bvh, accM, 0, 0, 0);
                        accS = __builtin_amdgcn_mfma_f32_16x16x32_f16(avl, bvh, accS, 0, 0, 0);
                        accS = __builtin_amdgcn_mfma_f32_16x16x32_f16(avh, bvl, accS, 0, 0, 0);
                    }
                }
            } else {
#pragma unroll
                for (int j = 0; j < 12; ++j) {
                    if (doh && j < 7) do_kd(hw, j, hk0, hk1);
                    if (domf) {
                        const int kt = 13 + j;
                        h8 avh = *(const h8*)(Ah + aoff + kt * 32);
                        h8 avl = *(const h8*)(Al + aoff + kt * 32);
                        h8 bvh = *(const h8*)(w1hi + boff + kt * 32);
                        h8 bvl = *(const h8*)(w1lo + boff + kt * 32);
                        accM = __builtin_amdgcn_mfma_f32_16x16x32_f16(avh, bvh, accM, 0, 0, 0);
                        accS = __builtin_amdgcn_mfma_f32_16x16x32_f16(avl, bvh, accS, 0, 0, 0);
                        accS = __builtin_amdgcn_mfma_f32_16x16x32_f16(avh, bvl, accS, 0, 0, 0);
                    }
                }
            }
            if (domf) {
                cc = accM + accS * 0.000244140625f;    // + accS/4096
                if (kh == 1) *(f4*)(red + (t & 1) * 1792 + nt * 256 + lane * 4) = cc;
            }
        } else {
            // waves 14,15: hash(t+1) + layer2(t-1)
            if (doh) {
                h16* hw = (h16*)(smem + ((t + 1) & 1) * 12928) + hrow * AS;
#pragma unroll
                for (int it = 0; it < 7; ++it) do_kd(hw, it, hk0, hk1);
            }
            if (t >= 1) {      // layer2 reads outer1(t-2) = o1s[t&1]
                const float* ob = o1s + (t & 1) * 1600;
                layer2(ob + r2a * H1, b2a, i2a, s2a, c2a, t >= 20);
                if (l2b) layer2(ob + r2b * H1, b2b, i2b, s2b, c2b, t >= 20);
            }
        }
        __syncthreads();
    }

    // ---- epilogue: log_softmax ----
    if (l2w) { sums[pa] = s2a; if (l2b) sums[pb] = s2b; }
    __syncthreads();
    if (tid < RT * H2) {
        const int rr = tid / 10, ccl = tid - 10 * rr;
        float m = -INFINITY;
#pragma unroll
        for (int cc2 = 0; cc2 < H2; ++cc2) m = fmaxf(m, sums[rr * H2 + cc2]);
        float s = 0.0f;
#pragma unroll
        for (int cc2 = 0; cc2 < H2; ++cc2) s += expf(sums[rr * H2 + cc2] - m);
        out[(row0 + rr) * H2 + ccl] = sums[rr * H2 + ccl] - m - logf(s);
    }
}

extern "C" void kernel_launch(void* const* d_in, const int* in_sizes, int n_in,
                              void* d_out, int out_size, void* d_ws, size_t ws_size,
                              hipStream_t stream) {
    const float* x  = (const float*)d_in[0];
    const float* W1 = (const float*)d_in[1];
    const float* b1 = (const float*)d_in[2];
    const float* W2 = (const float*)d_in[3];
    const float* b2 = (const float*)d_in[4];
    float* out = (float*)d_out;
    h16* w1hi = (h16*)d_ws;                          // 179,200 B
    h16* w1lo = w1hi + WROWS * WK;                   // ws total 358,400 B

    hipLaunchKernelGGL(prep_w1, dim3((WROWS * WK + 255) / 256), dim3(256), 0, stream,
                       W1, w1hi, w1lo);

    const size_t lds_bytes = (size_t)L_TOTAL * 4;    // 136,000 B
    hipFuncSetAttribute((const void*)spiking_net_kernel,
                        hipFuncAttributeMaxDynamicSharedMemorySize, (int)lds_bytes);
    // 256 blocks x 1024 threads (R10 topology); hash fused into MFMA kt-loop
    hipLaunchKernelGGL(spiking_net_kernel, dim3(BATCH / RT), dim3(1024), lds_bytes, stream,
                       x, w1hi, w1lo, b1, W2, b2, out);
}